// Round 5
// baseline (587.564 us; speedup 1.0000x reference)
//
#include <hip/hip_runtime.h>
#include <hip/hip_bf16.h>

typedef __bf16 bf16;
typedef __bf16 bf16x4 __attribute__((ext_vector_type(4)));
typedef __bf16 bf16x8 __attribute__((ext_vector_type(8)));
typedef float floatx4 __attribute__((ext_vector_type(4)));

#define MFMA16(a, b, c) __builtin_amdgcn_mfma_f32_16x16x32_bf16((a), (b), (c), 0, 0, 0)

// ---- workspace layout (bytes) ----
static constexpr long OFF_QKV   = 0;            // bf16 [65536][1536]  201326592
static constexpr long OFF_XB    = 201326592;    // bf16 [65536][512]   67108864 (attn_out)
static constexpr long OFF_WQKV  = 268435456;    // bf16 [1536][512]    1572864
static constexpr long OFF_WPROJ = 270008320;    // bf16 [512][512]     524288
static constexpr long OFF_BT    = 270532608;    // f32  [225][16]      (padded to 16384)
static constexpr long OFF_RB    = 270548992;    // f32  [16][64][64]   262144

__device__ __forceinline__ void load_lds16(const bf16* g, bf16* l) {
  // async global->LDS, 16B per lane; LDS dest is wave-uniform base + lane*16
  __builtin_amdgcn_global_load_lds((const __attribute__((address_space(1))) void*)(g),
                                   (__attribute__((address_space(3))) void*)(l), 16, 0, 0);
}

// ---------------- fp32 -> bf16 convert (8 elems/thread) ----------------
__global__ __launch_bounds__(256) void cvt_f32_bf16(const float* __restrict__ src,
                                                    bf16* __restrict__ dst, int n8) {
  int i = blockIdx.x * 256 + threadIdx.x;
  if (i < n8) {
    const float4* s = (const float4*)src;
    float4 a = s[2 * i], b = s[2 * i + 1];
    bf16x8 o;
    o[0] = (bf16)a.x; o[1] = (bf16)a.y; o[2] = (bf16)a.z; o[3] = (bf16)a.w;
    o[4] = (bf16)b.x; o[5] = (bf16)b.y; o[6] = (bf16)b.z; o[7] = (bf16)b.w;
    ((bf16x8*)dst)[i] = o;
  }
}

// ---------------- CPB-MLP: bias_table[225][16] ----------------
__global__ __launch_bounds__(256) void cpb_mlp(const float* __restrict__ table,
                                               const float* __restrict__ w1,
                                               const float* __restrict__ b1,
                                               const float* __restrict__ w2,
                                               float* __restrict__ bias_table) {
  __shared__ float hid[512];
  const int e = blockIdx.x;                   // 0..224
  const float t0 = table[e * 2 + 0], t1 = table[e * 2 + 1];
  for (int j = threadIdx.x; j < 512; j += 256) {
    float hv = t0 * w1[j * 2 + 0] + t1 * w1[j * 2 + 1] + b1[j];
    hid[j] = hv > 0.f ? hv : 0.f;
  }
  __syncthreads();
  const int hd = threadIdx.x >> 4, l = threadIdx.x & 15;
  float p = 0.f;
  for (int j = l; j < 512; j += 16) p += hid[j] * w2[hd * 512 + j];
  #pragma unroll
  for (int d = 8; d >= 1; d >>= 1) p += __shfl_xor(p, d, 16);
  if (l == 0) bias_table[e * 16 + hd] = p;
}

// ---------------- gather + sigmoid: rel_bias[16][64][64] ----------------
__global__ __launch_bounds__(256) void cpb_gather(const float* __restrict__ bias_table,
                                                  const int* __restrict__ idx,
                                                  float* __restrict__ rel_bias) {
  int f = blockIdx.x * 256 + threadIdx.x;     // 65536 total
  int h = f >> 12, ij = f & 4095;
  float v = bias_table[idx[ij] * 16 + h];
  rel_bias[f] = 16.f / (1.f + __expf(-v));
}

// ---------------- bf16 GEMM: C[M,NN] = A[M,512] @ Bt[NN,512]^T (+bias) ----------------
// R5: 256x256, 8 waves, 4-slot ring (slot = 256 rows x 32 k), m201-EXACT phase anatomy:
// per slice 2 phases, each {issue staging; issue ds_reads; s_barrier; lgkmcnt(0);
// setprio(1); 16 MFMA; setprio(0); s_barrier} — read-issue and MFMA in barrier-separated
// regions (m196: this fine interleave is the lever; R3/R4's same-region layout was null
// at MfmaUtil 26%). Counted vmcnt keeps next-slice loads in flight across barriers (T4).
// QKV=true additionally FUSES the fp32->bf16 convert of x into the A path (reg-staged:
// global fp32 loads -> cvt -> ds_write, same position/swizzle convention as gload_lds),
// deleting the 201MB cvt_x kernel + 67MB re-read. Ring safety: slot (h+1) ds_written in
// slice h phase1 before lgkmcnt(0)+barrier; first read slice h+1 phase0 (2 barriers
// later); overwrite 4 slices after last read. Grid: n-innermost per XCD chunk.
template <int NN, bool QKV>
__global__ __launch_bounds__(512, 2) void gemm_bt(const void* __restrict__ Ain,
                                                  const bf16* __restrict__ Bt,
                                                  void* __restrict__ outv,
                                                  const float* __restrict__ bias_a,
                                                  const float* __restrict__ bias_b) {
  constexpr int K = 512;
  constexpr int nblk = NN / 256;
  const float* Af = (const float*)Ain;   // QKV: x fp32
  const bf16*  Ab = (const bf16*)Ain;    // proj: attn_out bf16
  __shared__ alignas(16) bf16 As[4][8192];   // 64 KB: slot = 256 rows x 32 k
  __shared__ alignas(16) bf16 Bs[4][8192];   // 64 KB
  const int tid = threadIdx.x;
  const int lane = tid & 63;
  const int wv = tid >> 6;                // 0..7
  const int bid = blockIdx.x;
  const int xcd = bid & 7;
  const int g = bid >> 3;
  const int mb = xcd * 32 + g / nblk;     // n innermost: A-slab shared by nblk blocks
  const int nb = g % nblk;
  const long m0 = (long)mb * 256;
  const int n0 = nb * 256;
  const int wm = (wv >> 2) * 128;         // 2 M-waves, per-wave 128 rows
  const int wn = (wv & 3) * 64;           // 4 N-waves, per-wave 64 cols
  const int cl = lane & 15;
  const int cq = lane >> 4;
  const int wbase = tid & ~63;
  const int sx = (cq ^ ((cl >> 1) & 3)) << 3;   // read swizzle (0 bank conflicts, R3/R4)

  const floatx4 fzero = {0.f, 0.f, 0.f, 0.f};
  floatx4 acc[8][4];
  #pragma unroll
  for (int i = 0; i < 8; ++i)
    #pragma unroll
    for (int j = 0; j < 4; ++j) acc[i][j] = fzero;

  // staging positions p0=tid, p1=512+tid: row p>>2, stored grp p&3, logical grp XOR'd
  const int rp0 = tid >> 2;
  const int rp1 = rp0 + 128;
  const int gl0 = (tid & 3) ^ ((tid >> 3) & 3);   // same involution as read swizzle

  auto stageB = [&](int j) {
    const bf16* gb0 = Bt + (long)(n0 + rp0) * K + j * 32 + gl0 * 8;
    load_lds16(gb0, &Bs[j & 3][wbase * 8]);
    const bf16* gb1 = Bt + (long)(n0 + rp1) * K + j * 32 + gl0 * 8;
    load_lds16(gb1, &Bs[j & 3][(512 + wbase) * 8]);
  };
  auto stageA_gl = [&](int j) {   // proj A path (bf16 source)
    const bf16* ga0 = Ab + (m0 + rp0) * (long)K + j * 32 + gl0 * 8;
    load_lds16(ga0, &As[j & 3][wbase * 8]);
    const bf16* ga1 = Ab + (m0 + rp1) * (long)K + j * 32 + gl0 * 8;
    load_lds16(ga1, &As[j & 3][(512 + wbase) * 8]);
  };

  float4 a0, a1, a2, a3;   // QKV: in-flight fp32 A data (one slice, 16 VGPR)
  auto issueA = [&](int j) {   // load fp32 x for slice j
    const float4* s0 = (const float4*)(Af + (m0 + rp0) * (long)K + j * 32 + gl0 * 8);
    const float4* s1 = (const float4*)(Af + (m0 + rp1) * (long)K + j * 32 + gl0 * 8);
    a0 = s0[0]; a1 = s0[1]; a2 = s1[0]; a3 = s1[1];
  };
  auto writeA = [&](int j) {   // cvt + ds_write into slot j (compiler auto-waits loads)
    bf16x8 v0, v1;
    v0[0] = (bf16)a0.x; v0[1] = (bf16)a0.y; v0[2] = (bf16)a0.z; v0[3] = (bf16)a0.w;
    v0[4] = (bf16)a1.x; v0[5] = (bf16)a1.y; v0[6] = (bf16)a1.z; v0[7] = (bf16)a1.w;
    v1[0] = (bf16)a2.x; v1[1] = (bf16)a2.y; v1[2] = (bf16)a2.z; v1[3] = (bf16)a2.w;
    v1[4] = (bf16)a3.x; v1[5] = (bf16)a3.y; v1[6] = (bf16)a3.z; v1[7] = (bf16)a3.w;
    *(bf16x8*)&As[j & 3][tid * 8] = v0;          // pos p0: linear 16B/lane, conflict-free
    *(bf16x8*)&As[j & 3][(512 + tid) * 8] = v1;  // pos p1
  };

  // ---- prologue: slots 0..2 of B (0 of A via regs for QKV; 0..2 gload for proj) ----
  if constexpr (QKV) {
    issueA(0);
    stageB(0); stageB(1); stageB(2);
    writeA(0);                                        // auto vmcnt for a0..a3
    asm volatile("s_waitcnt vmcnt(4)" ::: "memory");  // B0 landed; B1,B2 in flight
    asm volatile("s_waitcnt lgkmcnt(0)" ::: "memory");// ds_writes visible
  } else {
    stageA_gl(0); stageB(0); stageA_gl(1); stageB(1); stageA_gl(2); stageB(2);
    asm volatile("s_waitcnt vmcnt(8)" ::: "memory");  // A0,B0 landed; slices 1,2 in flight
  }
  __builtin_amdgcn_s_barrier();

  #pragma unroll
  for (int h = 0; h < 16; ++h) {
    const int slot = h & 3;
    // ================= PHASE 0 =================
    if constexpr (QKV) {
      if (h + 1 <= 15) issueA(h + 1);     // fp32 loads, consumed at this slice's phase 1
    } else {
      if (h + 3 <= 15) stageA_gl(h + 3);
    }
    bf16x8 af0[4], bfr[4];
    #pragma unroll
    for (int m = 0; m < 4; ++m)
      af0[m] = *(const bf16x8*)&As[slot][(wm + m * 16 + cl) * 32 + sx];
    #pragma unroll
    for (int n = 0; n < 4; ++n)
      bfr[n] = *(const bf16x8*)&Bs[slot][(wn + n * 16 + cl) * 32 + sx];
    __builtin_amdgcn_s_barrier();                       // LDS drain under rendezvous
    asm volatile("s_waitcnt lgkmcnt(0)" ::: "memory");
    __builtin_amdgcn_sched_barrier(0);                  // rule 18 fence
    __builtin_amdgcn_s_setprio(1);
    #pragma unroll
    for (int i = 0; i < 4; ++i)
      #pragma unroll
      for (int j = 0; j < 4; ++j)
        acc[i][j] = MFMA16(bfr[j], af0[i], acc[i][j]);  // swapped: col-vector C layout
    __builtin_amdgcn_s_setprio(0);
    __builtin_amdgcn_s_barrier();
    __builtin_amdgcn_sched_barrier(0);
    // ================= PHASE 1 =================
    if (h + 3 <= 15) stageB(h + 3);
    if constexpr (QKV) {
      if (h <= 12) asm volatile("s_waitcnt vmcnt(2)" ::: "memory");  // keep B(h+3) flying
      if (h + 1 <= 15) writeA(h + 1);     // cvt + ds_write slot h+1 (pre-barrier)
    } else {
      if (h <= 12)      asm volatile("s_waitcnt vmcnt(8)" ::: "memory");
      else if (h == 13) asm volatile("s_waitcnt vmcnt(4)" ::: "memory");
      else if (h == 14) asm volatile("s_waitcnt vmcnt(0)" ::: "memory");
    }
    bf16x8 af1[4];
    #pragma unroll
    for (int m = 0; m < 4; ++m)
      af1[m] = *(const bf16x8*)&As[slot][(wm + 64 + m * 16 + cl) * 32 + sx];
    asm volatile("s_waitcnt lgkmcnt(0)" ::: "memory");  // writes visible BEFORE barrier
    __builtin_amdgcn_s_barrier();
    __builtin_amdgcn_sched_barrier(0);
    __builtin_amdgcn_s_setprio(1);
    #pragma unroll
    for (int i = 0; i < 4; ++i)
      #pragma unroll
      for (int j = 0; j < 4; ++j)
        acc[4 + i][j] = MFMA16(bfr[j], af1[i], acc[4 + i][j]);
    __builtin_amdgcn_s_setprio(0);
    if (h < 15) {
      __builtin_amdgcn_s_barrier();
      __builtin_amdgcn_sched_barrier(0);
    }
  }

  // epilogue: lane holds C[m0+wm+i*16+cl][n0+wn+j*16+cq*4 + r], r=0..3 consecutive cols
  const int cq4 = cq * 4;
  #pragma unroll
  for (int i = 0; i < 8; ++i) {
    const long m = m0 + wm + i * 16 + cl;
    #pragma unroll
    for (int j = 0; j < 4; ++j) {
      const int nbase = n0 + wn + j * 16 + cq4;
      if constexpr (QKV) {
        // qkv bias: [q_bias | zeros | v_bias]; 4-col group never straddles a boundary
        float4 bb = {0.f, 0.f, 0.f, 0.f};
        if (nbase < 512) bb = *(const float4*)&bias_a[nbase];
        else if (nbase >= 1024) bb = *(const float4*)&bias_b[nbase - 1024];
        bf16x4 o;
        o[0] = (bf16)(acc[i][j][0] + bb.x);
        o[1] = (bf16)(acc[i][j][1] + bb.y);
        o[2] = (bf16)(acc[i][j][2] + bb.z);
        o[3] = (bf16)(acc[i][j][3] + bb.w);
        *(bf16x4*)((bf16*)outv + m * NN + nbase) = o;
      } else {
        const float4 bb = *(const float4*)&bias_a[nbase];
        float4 o;
        o.x = acc[i][j][0] + bb.x;
        o.y = acc[i][j][1] + bb.y;
        o.z = acc[i][j][2] + bb.z;
        o.w = acc[i][j][3] + bb.w;
        *(float4*)((float*)outv + m * NN + nbase) = o;
      }
    }
  }
}

// ---------------- fused window attention: one block per (window, head) ----------------
// Head-pair XCD swizzle: (b,2j) and (b,2j+1) share 128B qkv cachelines; keep them on
// the same XCD, adjacent in dispatch order, so the second block hits L2.
// LDS pool 24.5KB (P aliases qh/ql after a barrier) -> 5-6 blocks/CU by LDS.
__global__ __launch_bounds__(256, 5) void attn_kernel(const bf16* __restrict__ qkv,
                                                      const float* __restrict__ mask,
                                                      const float* __restrict__ lscale,
                                                      const float* __restrict__ rel_bias,
                                                      bf16* __restrict__ out) {
  const int bid = blockIdx.x;
  const int xcd = bid & 7;
  const int t = bid >> 3;                  // 0..2047
  const int p = xcd + ((t >> 1) << 3);     // pair index 0..8191
  const int b = p >> 3;                    // window 0..1023
  const int h = ((p & 7) << 1) | (t & 1);  // head 0..15
  const int wi = b & 63;
  const int tid = threadIdx.x;
  const int lane = tid & 63;
  const int wv = tid >> 6;
  const int cl = lane & 15;
  const int cq = lane >> 4;

  // single pool: qh/ql/kh/kl [64x40] each, vT [32x72]; ps [64x72] aliases qh+ql
  __shared__ alignas(16) bf16 smem[12544];  // 25088 B
  bf16* qh_s = smem;            // 2560 elems
  bf16* ql_s = smem + 2560;
  bf16* kh_s = smem + 5120;
  bf16* kl_s = smem + 7680;
  bf16* vT   = smem + 10240;    // 2304 elems
  bf16* ps   = smem;            // 4608 elems, reused after barrier

  {  // stage + l2-normalize q,k (fp32 norm, hi/lo bf16 split); transpose v
    const int r = tid >> 2, seg = tid & 3;
    const bf16* base = qkv + (long)(b * 64 + r) * 1536 + h * 32 + seg * 8;
    float f[8], ss;
    bf16x8 hi, lo;

    bf16x8 qv = *(const bf16x8*)(base);
    ss = 0.f;
    #pragma unroll
    for (int j = 0; j < 8; ++j) { f[j] = (float)qv[j]; ss += f[j] * f[j]; }
    ss += __shfl_xor(ss, 1, 4); ss += __shfl_xor(ss, 2, 4);
    float s1 = 1.f / fmaxf(sqrtf(ss), 1e-12f);
    #pragma unroll
    for (int j = 0; j < 8; ++j) {
      float xn = f[j] * s1;
      bf16 xh = (bf16)xn;
      hi[j] = xh; lo[j] = (bf16)(xn - (float)xh);
    }
    *(bf16x8*)&qh_s[r * 40 + seg * 8] = hi;
    *(bf16x8*)&ql_s[r * 40 + seg * 8] = lo;

    bf16x8 kv = *(const bf16x8*)(base + 512);
    ss = 0.f;
    #pragma unroll
    for (int j = 0; j < 8; ++j) { f[j] = (float)kv[j]; ss += f[j] * f[j]; }
    ss += __shfl_xor(ss, 1, 4); ss += __shfl_xor(ss, 2, 4);
    s1 = 1.f / fmaxf(sqrtf(ss), 1e-12f);
    #pragma unroll
    for (int j = 0; j < 8; ++j) {
      float xn = f[j] * s1;
      bf16 xh = (bf16)xn;
      hi[j] = xh; lo[j] = (bf16)(xn - (float)xh);
    }
    *(bf16x8*)&kh_s[r * 40 + seg * 8] = hi;
    *(bf16x8*)&kl_s[r * 40 + seg * 8] = lo;

    bf16x8 vv = *(const bf16x8*)(base + 1024);
    #pragma unroll
    for (int j = 0; j < 8; ++j) vT[(seg * 8 + j) * 72 + r] = vv[j];
  }
  __syncthreads();

  const float sc = __expf(fminf(lscale[h], 4.6051701859880914f));  // exp(min(ls, ln 100))

  // QK^T for this wave's 16-row m-tile; 3-MFMA split-bf16 for accuracy
  const int mrow = wv * 16 + cl;
  const bf16x8 aqh = *(const bf16x8*)&qh_s[mrow * 40 + cq * 8];
  const bf16x8 aql = *(const bf16x8*)&ql_s[mrow * 40 + cq * 8];
  floatx4 sacc[4];
  #pragma unroll
  for (int nt = 0; nt < 4; ++nt) {
    const int nr = nt * 16 + cl;
    const bf16x8 bkh = *(const bf16x8*)&kh_s[nr * 40 + cq * 8];
    const bf16x8 bkl = *(const bf16x8*)&kl_s[nr * 40 + cq * 8];
    floatx4 a = {0.f, 0.f, 0.f, 0.f};
    a = MFMA16(aql, bkh, a);
    a = MFMA16(aqh, bkl, a);
    a = MFMA16(aqh, bkh, a);
    sacc[nt] = a;
  }
  __syncthreads();  // all waves done reading qh/ql/kh/kl before ps overwrites them

  // scale + rel_bias + mask, fp32 softmax over 64 cols (16 lanes x 4 nt)
  float pw[4][4];  // [rg][nt]
  #pragma unroll
  for (int rg = 0; rg < 4; ++rg) {
    const int row = wv * 16 + cq * 4 + rg;
    const float* rbp = rel_bias + h * 4096 + row * 64;
    const float* mkp = mask + wi * 4096 + row * 64;
    float mxv = -1e30f;
    #pragma unroll
    for (int nt = 0; nt < 4; ++nt) {
      float s = sacc[nt][rg] * sc + rbp[nt * 16 + cl] + mkp[nt * 16 + cl];
      pw[rg][nt] = s;
      mxv = fmaxf(mxv, s);
    }
    #pragma unroll
    for (int d = 8; d >= 1; d >>= 1) mxv = fmaxf(mxv, __shfl_xor(mxv, d, 16));
    float sm = 0.f;
    #pragma unroll
    for (int nt = 0; nt < 4; ++nt) {
      float e = __expf(pw[rg][nt] - mxv);
      pw[rg][nt] = e;
      sm += e;
    }
    #pragma unroll
    for (int d = 8; d >= 1; d >>= 1) sm += __shfl_xor(sm, d, 16);
    const float inv = 1.f / sm;
    #pragma unroll
    for (int nt = 0; nt < 4; ++nt)
      ps[row * 72 + nt * 16 + cl] = (bf16)(pw[rg][nt] * inv);
  }
  // no barrier needed: each wave reads back only its own 16 P-rows (within-wave lgkmcnt)

  // PV: O[64x32] = P[64x64] @ V[64x32] via vT; operands SWAPPED so each lane holds
  // 4 consecutive head-dims of one row -> 2x bf16x4 stores instead of 8 scalar
  floatx4 oacc[2];
  oacc[0] = (floatx4){0.f, 0.f, 0.f, 0.f};
  oacc[1] = (floatx4){0.f, 0.f, 0.f, 0.f};
  #pragma unroll
  for (int ks = 0; ks < 2; ++ks) {
    const bf16x8 ap = *(const bf16x8*)&ps[(wv * 16 + cl) * 72 + ks * 32 + cq * 8];
    #pragma unroll
    for (int nt = 0; nt < 2; ++nt) {
      const bf16x8 bv = *(const bf16x8*)&vT[(nt * 16 + cl) * 72 + ks * 32 + cq * 8];
      oacc[nt] = MFMA16(bv, ap, oacc[nt]);  // swapped: O^T fragment
    }
  }
  // lane holds O[wv*16 + cl][nt*16 + cq*4 + r]
  const long obase = (long)(b * 64 + wv * 16 + cl) * 512 + h * 32 + cq * 4;
  #pragma unroll
  for (int nt = 0; nt < 2; ++nt) {
    bf16x4 o;
    #pragma unroll
    for (int r = 0; r < 4; ++r) o[r] = (bf16)oacc[nt][r];
    *(bf16x4*)&out[obase + nt * 16] = o;
  }
}

extern "C" void kernel_launch(void* const* d_in, const int* in_sizes, int n_in,
                              void* d_out, int out_size, void* d_ws, size_t ws_size,
                              hipStream_t stream) {
  const float* x      = (const float*)d_in[0];
  const float* mask   = (const float*)d_in[1];
  const float* qkv_w  = (const float*)d_in[2];
  const float* q_bias = (const float*)d_in[3];
  const float* v_bias = (const float*)d_in[4];
  const float* lsc    = (const float*)d_in[5];
  const float* cpb_w1 = (const float*)d_in[6];
  const float* cpb_b1 = (const float*)d_in[7];
  const float* cpb_w2 = (const float*)d_in[8];
  const float* proj_w = (const float*)d_in[9];
  const float* proj_b = (const float*)d_in[10];
  const float* table  = (const float*)d_in[11];
  const int*   relidx = (const int*)d_in[12];

  char* ws = (char*)d_ws;
  bf16* qkvb   = (bf16*)(ws + OFF_QKV);
  bf16* xb     = (bf16*)(ws + OFF_XB);   // attn_out
  bf16* wqkv   = (bf16*)(ws + OFF_WQKV);
  bf16* wproj  = (bf16*)(ws + OFF_WPROJ);
  float* btab  = (float*)(ws + OFF_BT);
  float* rbias = (float*)(ws + OFF_RB);

  cvt_f32_bf16<<<384, 256, 0, stream>>>(qkv_w, wqkv, 1536 * 512 / 8);
  cvt_f32_bf16<<<128, 256, 0, stream>>>(proj_w, wproj, 512 * 512 / 8);
  cpb_mlp<<<225, 256, 0, stream>>>(table, cpb_w1, cpb_b1, cpb_w2, btab);
  cpb_gather<<<256, 256, 0, stream>>>(btab, relidx, rbias);

  // QKV = x @ qkv_w^T + [q_bias|0|v_bias] -> bf16 (fp32->bf16 convert fused into A path)
  gemm_bt<1536, true><<<1536, 512, 0, stream>>>((const void*)x, wqkv, (void*)qkvb,
                                                q_bias, v_bias);
  // fused cosine attention + bias + mask + softmax + PV -> bf16 [65536][512]
  attn_kernel<<<16384, 256, 0, stream>>>(qkvb, mask, lsc, rbias, xb);
  // out = attn_out @ proj_w^T + proj_b -> fp32
  gemm_bt<512, false><<<512, 512, 0, stream>>>((const void*)xb, wproj, d_out,
                                               proj_b, nullptr);
}

// Round 6
// 552.278 us; speedup vs baseline: 1.0639x; 1.0639x over previous
//
#include <hip/hip_runtime.h>
#include <hip/hip_bf16.h>

typedef __bf16 bf16;
typedef __bf16 bf16x4 __attribute__((ext_vector_type(4)));
typedef __bf16 bf16x8 __attribute__((ext_vector_type(8)));
typedef float floatx4 __attribute__((ext_vector_type(4)));

#define MFMA16(a, b, c) __builtin_amdgcn_mfma_f32_16x16x32_bf16((a), (b), (c), 0, 0, 0)

// ---- workspace layout (bytes) ----
static constexpr long OFF_QKV   = 0;            // bf16 [65536][1536]  201326592
static constexpr long OFF_XB    = 201326592;    // bf16 [65536][512]   67108864 (x_bf16, later attn_out)
static constexpr long OFF_WQKV  = 268435456;    // bf16 [1536][512]    1572864
static constexpr long OFF_WPROJ = 270008320;    // bf16 [512][512]     524288
static constexpr long OFF_BT    = 270532608;    // f32  [225][16]      (padded to 16384)
static constexpr long OFF_RB    = 270548992;    // f32  [16][64][64]   262144

__device__ __forceinline__ void load_lds16(const bf16* g, bf16* l) {
  // async global->LDS, 16B per lane; LDS dest is wave-uniform base + lane*16
  __builtin_amdgcn_global_load_lds((const __attribute__((address_space(1))) void*)(g),
                                   (__attribute__((address_space(3))) void*)(l), 16, 0, 0);
}

// ---------------- fp32 -> bf16 convert (8 elems/thread) ----------------
__global__ __launch_bounds__(256) void cvt_f32_bf16(const float* __restrict__ src,
                                                    bf16* __restrict__ dst, int n8) {
  int i = blockIdx.x * 256 + threadIdx.x;
  if (i < n8) {
    const float4* s = (const float4*)src;
    float4 a = s[2 * i], b = s[2 * i + 1];
    bf16x8 o;
    o[0] = (bf16)a.x; o[1] = (bf16)a.y; o[2] = (bf16)a.z; o[3] = (bf16)a.w;
    o[4] = (bf16)b.x; o[5] = (bf16)b.y; o[6] = (bf16)b.z; o[7] = (bf16)b.w;
    ((bf16x8*)dst)[i] = o;
  }
}

// ---------------- CPB-MLP: bias_table[225][16] ----------------
__global__ __launch_bounds__(256) void cpb_mlp(const float* __restrict__ table,
                                               const float* __restrict__ w1,
                                               const float* __restrict__ b1,
                                               const float* __restrict__ w2,
                                               float* __restrict__ bias_table) {
  __shared__ float hid[512];
  const int e = blockIdx.x;                   // 0..224
  const float t0 = table[e * 2 + 0], t1 = table[e * 2 + 1];
  for (int j = threadIdx.x; j < 512; j += 256) {
    float hv = t0 * w1[j * 2 + 0] + t1 * w1[j * 2 + 1] + b1[j];
    hid[j] = hv > 0.f ? hv : 0.f;
  }
  __syncthreads();
  const int hd = threadIdx.x >> 4, l = threadIdx.x & 15;
  float p = 0.f;
  for (int j = l; j < 512; j += 16) p += hid[j] * w2[hd * 512 + j];
  #pragma unroll
  for (int d = 8; d >= 1; d >>= 1) p += __shfl_xor(p, d, 16);
  if (l == 0) bias_table[e * 16 + hd] = p;
}

// ---------------- gather + sigmoid: rel_bias[16][64][64] ----------------
__global__ __launch_bounds__(256) void cpb_gather(const float* __restrict__ bias_table,
                                                  const int* __restrict__ idx,
                                                  float* __restrict__ rel_bias) {
  int f = blockIdx.x * 256 + threadIdx.x;     // 65536 total
  int h = f >> 12, ij = f & 4095;
  float v = bias_table[idx[ij] * 16 + h];
  rel_bias[f] = 16.f / (1.f + __expf(-v));
}

// ---------------- bf16 GEMM: C[M,NN] = A[M,512] @ Bt[NN,512]^T (+bias) ----------------
// R6: OCCUPANCY over deep pipelining. Resource-envelope arithmetic: the 256x256 tile's
// 128x64 wave tile needs acc=128 regs -> >128 regs/wave -> 1 block/CU -> zero TLP; five
// structure variants all pinned at MfmaUtil 23-27% with ~4.1K cyc/slice (vs R0's 1.1K
// at 3 blocks/CU: TLP beats source-level pipelining on this compiler). New config:
// 128x128 tile, 4 waves (256 thr), 64x64 wave tile (acc=64 regs), BK=32 double-buffer
// (32KB LDS) -> __launch_bounds__(256,4) = 4 blocks/CU, 16 waves. Aggregate model:
// LDS/CU/slice 131KB -> ~512 cyc at 256B/clk; MFMA 4.2MF -> ~1082 cyc -> MFMA-BOUND,
// with inter-block TLP covering vmcnt(0)/barrier drains. Also fixes proj's tail: grid
// 512 -> 2048 blocks (R4-proj: 2 sequential blocks/CU at 1 resident = fully exposed).
// Per slice: {stage(h+1) 4x gload_lds; 8x ds_read_b128 (XOR-swizzled, ~conflict-free);
// 16 MFMA (setprio); vmcnt(0); barrier}. Epilogue: swapped-operand vector stores.
template <int NN, bool QKV>
__global__ __launch_bounds__(256, 4) void gemm_bt(const bf16* __restrict__ A,
                                                  const bf16* __restrict__ Bt,
                                                  void* __restrict__ outv,
                                                  const float* __restrict__ bias_a,
                                                  const float* __restrict__ bias_b) {
  constexpr int K = 512;
  constexpr int KT = K / 32;              // 16 k-slices
  constexpr int nblk = NN / 128;
  __shared__ alignas(16) bf16 As[2][128 * 32];   // 2 x 8KB
  __shared__ alignas(16) bf16 Bs[2][128 * 32];   // 2 x 8KB
  const int tid = threadIdx.x;
  const int lane = tid & 63;
  const int wv = tid >> 6;                // 0..3
  const int bid = blockIdx.x;
  const int xcd = bid & 7;
  const int g = bid >> 3;                 // 0 .. 64*nblk-1
  const int mb = xcd * 64 + g / nblk;     // n innermost: A-slab shared by nblk blocks
  const int nb = g % nblk;
  const long m0 = (long)mb * 128;
  const int n0 = nb * 128;
  const int wm = (wv & 1) * 64;
  const int wn = (wv >> 1) * 64;
  const int cl = lane & 15;
  const int cq = lane >> 4;
  const int wbase = tid & ~63;

  const floatx4 fzero = {0.f, 0.f, 0.f, 0.f};
  floatx4 acc[4][4];
  #pragma unroll
  for (int i = 0; i < 4; ++i)
    #pragma unroll
    for (int j = 0; j < 4; ++j) acc[i][j] = fzero;

  // staging: position s = r*256+tid covers (row = s>>2, stored k-grp = s&3);
  // logical grp gl = (s&3) ^ (row&3) (involution) -> read swizzle sx = cq ^ (cl&3)
  int srow[2], sgl[2];
  #pragma unroll
  for (int r = 0; r < 2; ++r) {
    const int s = r * 256 + tid;
    srow[r] = s >> 2;
    sgl[r] = (s & 3) ^ ((s >> 2) & 3);
  }
  const int sx = cq ^ (cl & 3);

  auto stage = [&](int buf, int j) {
    const int k0 = j * 32;
    #pragma unroll
    for (int r = 0; r < 2; ++r) {
      const bf16* ga = A + (m0 + srow[r]) * (long)K + (k0 + sgl[r] * 8);
      load_lds16(ga, &As[buf][(r * 256 + wbase) * 8]);
      const bf16* gb = Bt + (long)(n0 + srow[r]) * K + (k0 + sgl[r] * 8);
      load_lds16(gb, &Bs[buf][(r * 256 + wbase) * 8]);
    }
  };

  stage(0, 0);
  asm volatile("s_waitcnt vmcnt(0)" ::: "memory");
  __builtin_amdgcn_s_barrier();

  #pragma unroll
  for (int h = 0; h < KT; ++h) {
    const int buf = h & 1;
    if (h + 1 < KT) stage(buf ^ 1, h + 1);   // prefetch next slice into other buffer
    bf16x8 af[4], bfr[4];
    #pragma unroll
    for (int t = 0; t < 4; ++t) {
      const int mr = wm + t * 16 + cl;
      af[t] = *(const bf16x8*)&As[buf][(mr * 4 + sx) * 8];
      const int nr = wn + t * 16 + cl;
      bfr[t] = *(const bf16x8*)&Bs[buf][(nr * 4 + sx) * 8];
    }
    __builtin_amdgcn_s_setprio(1);
    #pragma unroll
    for (int i = 0; i < 4; ++i)
      #pragma unroll
      for (int j = 0; j < 4; ++j)
        acc[i][j] = MFMA16(bfr[j], af[i], acc[i][j]);   // swapped: col-vector C layout
    __builtin_amdgcn_s_setprio(0);
    if (h + 1 < KT) {
      asm volatile("s_waitcnt vmcnt(0)" ::: "memory");  // next slice landed (TLP covers)
      __builtin_amdgcn_s_barrier();
    }
  }

  // epilogue: lane holds C[m0+wm+i*16+cl][n0+wn+j*16+cq*4 + r], r=0..3 consecutive cols
  const int cq4 = cq * 4;
  #pragma unroll
  for (int i = 0; i < 4; ++i) {
    const long m = m0 + wm + i * 16 + cl;
    #pragma unroll
    for (int j = 0; j < 4; ++j) {
      const int nbase = n0 + wn + j * 16 + cq4;
      if constexpr (QKV) {
        // qkv bias: [q_bias | zeros | v_bias]; 4-col group never straddles a boundary
        float4 bb = {0.f, 0.f, 0.f, 0.f};
        if (nbase < 512) bb = *(const float4*)&bias_a[nbase];
        else if (nbase >= 1024) bb = *(const float4*)&bias_b[nbase - 1024];
        bf16x4 o;
        o[0] = (bf16)(acc[i][j][0] + bb.x);
        o[1] = (bf16)(acc[i][j][1] + bb.y);
        o[2] = (bf16)(acc[i][j][2] + bb.z);
        o[3] = (bf16)(acc[i][j][3] + bb.w);
        *(bf16x4*)((bf16*)outv + m * NN + nbase) = o;
      } else {
        const float4 bb = *(const float4*)&bias_a[nbase];
        float4 o;
        o.x = acc[i][j][0] + bb.x;
        o.y = acc[i][j][1] + bb.y;
        o.z = acc[i][j][2] + bb.z;
        o.w = acc[i][j][3] + bb.w;
        *(float4*)((float*)outv + m * NN + nbase) = o;
      }
    }
  }
}

// ---------------- fused window attention: one block per (window, head) ----------------
// Head-pair XCD swizzle: (b,2j) and (b,2j+1) share 128B qkv cachelines; keep them on
// the same XCD, adjacent in dispatch order, so the second block hits L2.
// LDS pool 24.5KB (P aliases qh/ql after a barrier) -> 5-6 blocks/CU by LDS.
__global__ __launch_bounds__(256, 5) void attn_kernel(const bf16* __restrict__ qkv,
                                                      const float* __restrict__ mask,
                                                      const float* __restrict__ lscale,
                                                      const float* __restrict__ rel_bias,
                                                      bf16* __restrict__ out) {
  const int bid = blockIdx.x;
  const int xcd = bid & 7;
  const int t = bid >> 3;                  // 0..2047
  const int p = xcd + ((t >> 1) << 3);     // pair index 0..8191
  const int b = p >> 3;                    // window 0..1023
  const int h = ((p & 7) << 1) | (t & 1);  // head 0..15
  const int wi = b & 63;
  const int tid = threadIdx.x;
  const int lane = tid & 63;
  const int wv = tid >> 6;
  const int cl = lane & 15;
  const int cq = lane >> 4;

  // single pool: qh/ql/kh/kl [64x40] each, vT [32x72]; ps [64x72] aliases qh+ql
  __shared__ alignas(16) bf16 smem[12544];  // 25088 B
  bf16* qh_s = smem;            // 2560 elems
  bf16* ql_s = smem + 2560;
  bf16* kh_s = smem + 5120;
  bf16* kl_s = smem + 7680;
  bf16* vT   = smem + 10240;    // 2304 elems
  bf16* ps   = smem;            // 4608 elems, reused after barrier

  {  // stage + l2-normalize q,k (fp32 norm, hi/lo bf16 split); transpose v
    const int r = tid >> 2, seg = tid & 3;
    const bf16* base = qkv + (long)(b * 64 + r) * 1536 + h * 32 + seg * 8;
    float f[8], ss;
    bf16x8 hi, lo;

    bf16x8 qv = *(const bf16x8*)(base);
    ss = 0.f;
    #pragma unroll
    for (int j = 0; j < 8; ++j) { f[j] = (float)qv[j]; ss += f[j] * f[j]; }
    ss += __shfl_xor(ss, 1, 4); ss += __shfl_xor(ss, 2, 4);
    float s1 = 1.f / fmaxf(sqrtf(ss), 1e-12f);
    #pragma unroll
    for (int j = 0; j < 8; ++j) {
      float xn = f[j] * s1;
      bf16 xh = (bf16)xn;
      hi[j] = xh; lo[j] = (bf16)(xn - (float)xh);
    }
    *(bf16x8*)&qh_s[r * 40 + seg * 8] = hi;
    *(bf16x8*)&ql_s[r * 40 + seg * 8] = lo;

    bf16x8 kv = *(const bf16x8*)(base + 512);
    ss = 0.f;
    #pragma unroll
    for (int j = 0; j < 8; ++j) { f[j] = (float)kv[j]; ss += f[j] * f[j]; }
    ss += __shfl_xor(ss, 1, 4); ss += __shfl_xor(ss, 2, 4);
    s1 = 1.f / fmaxf(sqrtf(ss), 1e-12f);
    #pragma unroll
    for (int j = 0; j < 8; ++j) {
      float xn = f[j] * s1;
      bf16 xh = (bf16)xn;
      hi[j] = xh; lo[j] = (bf16)(xn - (float)xh);
    }
    *(bf16x8*)&kh_s[r * 40 + seg * 8] = hi;
    *(bf16x8*)&kl_s[r * 40 + seg * 8] = lo;

    bf16x8 vv = *(const bf16x8*)(base + 1024);
    #pragma unroll
    for (int j = 0; j < 8; ++j) vT[(seg * 8 + j) * 72 + r] = vv[j];
  }
  __syncthreads();

  const float sc = __expf(fminf(lscale[h], 4.6051701859880914f));  // exp(min(ls, ln 100))

  // QK^T for this wave's 16-row m-tile; 3-MFMA split-bf16 for accuracy
  const int mrow = wv * 16 + cl;
  const bf16x8 aqh = *(const bf16x8*)&qh_s[mrow * 40 + cq * 8];
  const bf16x8 aql = *(const bf16x8*)&ql_s[mrow * 40 + cq * 8];
  floatx4 sacc[4];
  #pragma unroll
  for (int nt = 0; nt < 4; ++nt) {
    const int nr = nt * 16 + cl;
    const bf16x8 bkh = *(const bf16x8*)&kh_s[nr * 40 + cq * 8];
    const bf16x8 bkl = *(const bf16x8*)&kl_s[nr * 40 + cq * 8];
    floatx4 a = {0.f, 0.f, 0.f, 0.f};
    a = MFMA16(aql, bkh, a);
    a = MFMA16(aqh, bkl, a);
    a = MFMA16(aqh, bkh, a);
    sacc[nt] = a;
  }
  __syncthreads();  // all waves done reading qh/ql/kh/kl before ps overwrites them

  // scale + rel_bias + mask, fp32 softmax over 64 cols (16 lanes x 4 nt)
  float pw[4][4];  // [rg][nt]
  #pragma unroll
  for (int rg = 0; rg < 4; ++rg) {
    const int row = wv * 16 + cq * 4 + rg;
    const float* rbp = rel_bias + h * 4096 + row * 64;
    const float* mkp = mask + wi * 4096 + row * 64;
    float mxv = -1e30f;
    #pragma unroll
    for (int nt = 0; nt < 4; ++nt) {
      float s = sacc[nt][rg] * sc + rbp[nt * 16 + cl] + mkp[nt * 16 + cl];
      pw[rg][nt] = s;
      mxv = fmaxf(mxv, s);
    }
    #pragma unroll
    for (int d = 8; d >= 1; d >>= 1) mxv = fmaxf(mxv, __shfl_xor(mxv, d, 16));
    float sm = 0.f;
    #pragma unroll
    for (int nt = 0; nt < 4; ++nt) {
      float e = __expf(pw[rg][nt] - mxv);
      pw[rg][nt] = e;
      sm += e;
    }
    #pragma unroll
    for (int d = 8; d >= 1; d >>= 1) sm += __shfl_xor(sm, d, 16);
    const float inv = 1.f / sm;
    #pragma unroll
    for (int nt = 0; nt < 4; ++nt)
      ps[row * 72 + nt * 16 + cl] = (bf16)(pw[rg][nt] * inv);
  }
  // no barrier needed: each wave reads back only its own 16 P-rows (within-wave lgkmcnt)

  // PV: O[64x32] = P[64x64] @ V[64x32] via vT; operands SWAPPED so each lane holds
  // 4 consecutive head-dims of one row -> 2x bf16x4 stores instead of 8 scalar
  floatx4 oacc[2];
  oacc[0] = (floatx4){0.f, 0.f, 0.f, 0.f};
  oacc[1] = (floatx4){0.f, 0.f, 0.f, 0.f};
  #pragma unroll
  for (int ks = 0; ks < 2; ++ks) {
    const bf16x8 ap = *(const bf16x8*)&ps[(wv * 16 + cl) * 72 + ks * 32 + cq * 8];
    #pragma unroll
    for (int nt = 0; nt < 2; ++nt) {
      const bf16x8 bv = *(const bf16x8*)&vT[(nt * 16 + cl) * 72 + ks * 32 + cq * 8];
      oacc[nt] = MFMA16(bv, ap, oacc[nt]);  // swapped: O^T fragment
    }
  }
  // lane holds O[wv*16 + cl][nt*16 + cq*4 + r]
  const long obase = (long)(b * 64 + wv * 16 + cl) * 512 + h * 32 + cq * 4;
  #pragma unroll
  for (int nt = 0; nt < 2; ++nt) {
    bf16x4 o;
    #pragma unroll
    for (int r = 0; r < 4; ++r) o[r] = (bf16)oacc[nt][r];
    *(bf16x4*)&out[obase + nt * 16] = o;
  }
}

extern "C" void kernel_launch(void* const* d_in, const int* in_sizes, int n_in,
                              void* d_out, int out_size, void* d_ws, size_t ws_size,
                              hipStream_t stream) {
  const float* x      = (const float*)d_in[0];
  const float* mask   = (const float*)d_in[1];
  const float* qkv_w  = (const float*)d_in[2];
  const float* q_bias = (const float*)d_in[3];
  const float* v_bias = (const float*)d_in[4];
  const float* lsc    = (const float*)d_in[5];
  const float* cpb_w1 = (const float*)d_in[6];
  const float* cpb_b1 = (const float*)d_in[7];
  const float* cpb_w2 = (const float*)d_in[8];
  const float* proj_w = (const float*)d_in[9];
  const float* proj_b = (const float*)d_in[10];
  const float* table  = (const float*)d_in[11];
  const int*   relidx = (const int*)d_in[12];

  char* ws = (char*)d_ws;
  bf16* qkvb   = (bf16*)(ws + OFF_QKV);
  bf16* xb     = (bf16*)(ws + OFF_XB);   // x_bf16, then reused as attn_out
  bf16* wqkv   = (bf16*)(ws + OFF_WQKV);
  bf16* wproj  = (bf16*)(ws + OFF_WPROJ);
  float* btab  = (float*)(ws + OFF_BT);
  float* rbias = (float*)(ws + OFF_RB);

  cvt_f32_bf16<<<16384, 256, 0, stream>>>(x, xb, 65536 * 512 / 8);
  cvt_f32_bf16<<<384, 256, 0, stream>>>(qkv_w, wqkv, 1536 * 512 / 8);
  cvt_f32_bf16<<<128, 256, 0, stream>>>(proj_w, wproj, 512 * 512 / 8);
  cpb_mlp<<<225, 256, 0, stream>>>(table, cpb_w1, cpb_b1, cpb_w2, btab);
  cpb_gather<<<256, 256, 0, stream>>>(btab, relidx, rbias);

  // QKV = x_bf16 @ qkv_w^T + [q_bias|0|v_bias]  -> bf16 [65536][1536]
  gemm_bt<1536, true><<<6144, 256, 0, stream>>>(xb, wqkv, (void*)qkvb, q_bias, v_bias);
  // fused cosine attention + bias + mask + softmax + PV -> bf16 [65536][512] (reuses xb)
  attn_kernel<<<16384, 256, 0, stream>>>(qkvb, mask, lsc, rbias, xb);
  // out = attn_out @ proj_w^T + proj_b -> fp32
  gemm_bt<512, false><<<2048, 256, 0, stream>>>(xb, wproj, d_out, proj_b, nullptr);
}